// Round 16
// baseline (336.052 us; speedup 1.0000x reference)
//
#include <hip/hip_runtime.h>
#include <stdint.h>

static constexpr int HIN = 256, WIN = 256, HO = 254, WOUT = 254, NB = 8;
static constexpr int PLANE = HO * WOUT;       // 64516
static constexpr int PIX = NB * PLANE;        // 516128

typedef float f32x4 __attribute__((ext_vector_type(4)));
typedef float f32x2 __attribute__((ext_vector_type(2)));

// Round-7 validated kernel with ONE change: the conv inner loop uses packed
// f32x2 FMA (v_pk_fma_f32), two atoms per instruction. Each half of every
// packed register is its own strictly sequential (ky,kx,c)-ordered FMA chain,
// so per-atom rounding is bit-identical to the scalar version (per-lane IEEE
// fma == __fmaf_rn). Differences vs the failed round-2 packed attempt:
// weights arrive as f32x4 VMEM loads (halves are pre-aligned register pairs,
// no v_mov repacking), px lives in LDS (not 27 registers), and
// __launch_bounds__(128,3) gives the allocator ~170-reg headroom (round 12
// showed (128,3) is perf-neutral vs (128,4)). All accumulator element
// accesses use compile-time indices (fully unrolled loops) — no scratch.
__device__ __align__(16) float g_wPad[4 * 27 * 64];
__device__ float g_bPad[4 * 64];

__constant__ int cN[4]   = {8, 16, 32, 64};
__constant__ int cK[4]   = {2, 4, 8, 16};
__constant__ int cCH0[4] = {0, 8, 24, 56};

// g_wPad[L][s][j] = w[(ch0_L+j)*27 + t(s)] for j<N_L else 0, where step
// s = ky*9+kx*3+c enumerates the VALIDATED (ky,kx,c) FMA order and
// t(s) = c*9+ky*3+kx is the source (c,ky,kx) layout offset.
__global__ void wprep(const float* __restrict__ w, const float* __restrict__ b) {
  int i = blockIdx.x * blockDim.x + threadIdx.x;
  if (i < 4 * 64) {
    int L = i / 64, j = i % 64;
    int N = 8 << L;
    int ch0 = (L == 0) ? 0 : (L == 1) ? 8 : (L == 2) ? 24 : 56;
    g_bPad[i] = (j < N) ? b[ch0 + j] : 0.0f;
  }
  if (i >= 4 * 27 * 64) return;
  int L = i / (27 * 64), r = i % (27 * 64), s = r / 64, j = r % 64;
  int N = 8 << L;
  int ch0 = (L == 0) ? 0 : (L == 1) ? 8 : (L == 2) ? 24 : 56;
  int ky = s / 9, kx = (s / 3) % 3, c = s % 3;
  g_wPad[i] = (j < N) ? w[(size_t)(ch0 + j) * 27 + c * 9 + ky * 3 + kx] : 0.0f;
}

// Ring connectivity: prev atom j feeds next atoms (2j..2j+3) mod a_next.
__device__ __forceinline__ uint64_t spread_pairs(uint64_t mask, int a_next) {
  uint64_t s = mask;
  s = (s | (s << 16)) & 0x0000FFFF0000FFFFull;
  s = (s | (s << 8))  & 0x00FF00FF00FF00FFull;
  s = (s | (s << 4))  & 0x0F0F0F0F0F0F0F0Full;
  s = (s | (s << 2))  & 0x3333333333333333ull;
  s = (s | (s << 1))  & 0x5555555555555555ull;
  uint64_t pair = s | (s << 1);
  uint64_t lim = (a_next >= 64) ? ~0ull : ((1ull << a_next) - 1ull);
  uint64_t rot = ((pair << 2) | (pair >> (a_next - 2))) & lim;
  return (pair | rot) & lim;
}

// Bitonic sort (descending) of 16 uint32 in registers; fully unrolled, static
// indices, pure v_min_u32/v_max_u32.
__device__ __forceinline__ void bsort16(uint32_t (&v)[16]) {
#pragma unroll
  for (int sz = 2; sz <= 16; sz <<= 1) {
#pragma unroll
    for (int st = sz >> 1; st > 0; st >>= 1) {
#pragma unroll
      for (int i = 0; i < 16; ++i) {
        int l = i ^ st;
        if (l > i) {
          uint32_t a = v[i], c = v[l];
          uint32_t mx = a > c ? a : c;
          uint32_t mn = a > c ? c : a;
          bool desc = ((i & sz) == 0);
          v[i] = desc ? mx : mn;
          v[l] = desc ? mn : mx;
        }
      }
    }
  }
}

__device__ __forceinline__ void bmerge16(uint32_t (&v)[16]) {
#pragma unroll
  for (int st = 8; st > 0; st >>= 1) {
#pragma unroll
    for (int i = 0; i < 16; ++i) {
      int l = i ^ st;
      if (l > i) {
        uint32_t a = v[i], c = v[l];
        v[i] = a > c ? a : c;
        v[l] = a > c ? c : a;
      }
    }
  }
}

// ACT(j): channel j of the packed accumulator file (compile-time j only).
#define ACT(j) act2[(j) >> 1][(j) & 1]

// Conv numerics (validated): per atom, single f32 accumulator from 0,
// sequential fma in (ky,kx,c) step order, bias added last as a separate
// __fadd_rn. Selection: jax top_k semantics — exactly K kept, boundary ties
// broken toward LOWEST channel index; run[] = sorted top-16 multiset of
// |act|, m = run[K-1], quota = #{i<K: run[i]==m}. Padded atoms (act==0) can
// only consume quota AFTER all real atoms and only when m==0; their stores
// hit later-level channels that this thread overwrites afterward.
__global__ __launch_bounds__(128, 3)
void hrtk_main(const float* __restrict__ x, float* __restrict__ out) {
  __shared__ float smem[128 * 27];   // 13824 B/block
  int p = blockIdx.x * blockDim.x + threadIdx.x;
  if (p >= PIX) return;
  int bi = p / PLANE;
  int r  = p % PLANE;
  int h  = r / WOUT;
  int wc = r % WOUT;

  // Stage the 3x3x3 patch into LDS in step order s = ky*9+kx*3+c (value from
  // source (c,ky,kx)) — matches g_wPad's step enumeration exactly.
  // Per-thread row, stride 27 words (odd) -> exactly 2 lanes/bank (free).
  float* pxl = &smem[threadIdx.x * 27];
  const float* xb = x + (size_t)bi * 3 * HIN * WIN;
#pragma unroll
  for (int ky = 0; ky < 3; ++ky)
#pragma unroll
    for (int kx = 0; kx < 3; ++kx)
#pragma unroll
      for (int c = 0; c < 3; ++c)
        pxl[ky * 9 + kx * 3 + c] =
            xb[c * HIN * WIN + (size_t)(h + ky) * WIN + (wc + kx)];

  // Per-thread 32-bit BYTE offset within out; per-channel base is uniform ->
  // global_store saddr form (SGPR base + 32-bit voffset), no per-store VALU.
  uint32_t tofs4 = (uint32_t)(bi * 120 * PLANE + r) * 4u;
  char* outB = (char*)out;
  uint64_t allow = ~0ull;   // level 0 ungated

#pragma unroll 1
  for (int lvl = 0; lvl < 4; ++lvl) {
    const int N = cN[lvl], K = cK[lvl], ch0 = cCH0[lvl];
    const float* wL = g_wPad + lvl * 27 * 64;
    const float* bL = g_bPad + lvl * 64;

    f32x2 act2[32];                    // channels {2k,2k+1} per element
#pragma unroll
    for (int q = 0; q < 4; ++q)
      if (q * 16 < N) {
#pragma unroll
        for (int k = 0; k < 8; ++k) { act2[q * 8 + k].x = 0.0f; act2[q * 8 + k].y = 0.0f; }
      }

    // ---- conv: 3 rolled s-groups of 9; pw[9] batch-read from LDS; weights
    // as per-lane f32x4 global loads; PACKED f32x2 FMA — 8 v_pk_fma_f32 per
    // (q,ss) instead of 16 v_fma_f32. Halves of each f32x4 load are
    // pre-aligned register pairs (no repacking). ----
#pragma unroll 1
    for (int g3 = 0; g3 < 3; ++g3) {
      const float* pg = pxl + g3 * 9;
      float pw[9];
#pragma unroll
      for (int ss = 0; ss < 9; ++ss) pw[ss] = pg[ss];
      const float* wg = wL + g3 * 9 * 64;
#pragma unroll
      for (int q = 0; q < 4; ++q)
        if (q * 16 < N) {
#pragma unroll
          for (int ss = 0; ss < 9; ++ss) {
            const f32x4* wr = (const f32x4*)(wg + ss * 64 + q * 16);
            f32x2 pv; pv.x = pw[ss]; pv.y = pw[ss];
#pragma unroll
            for (int v4 = 0; v4 < 4; ++v4) {
              f32x4 wv = wr[v4];
              f32x2 wlo; wlo.x = wv.x; wlo.y = wv.y;
              f32x2 whi; whi.x = wv.z; whi.y = wv.w;
              act2[q * 8 + v4 * 2 + 0] =
                  __builtin_elementwise_fma(pv, wlo, act2[q * 8 + v4 * 2 + 0]);
              act2[q * 8 + v4 * 2 + 1] =
                  __builtin_elementwise_fma(pv, whi, act2[q * 8 + v4 * 2 + 1]);
            }
          }
        }
    }

    // ---- bias + gate (scalar, compile-time element indices) ----
#pragma unroll
    for (int q = 0; q < 4; ++q)
      if (q * 16 < N) {
#pragma unroll
        for (int i = 0; i < 16; ++i) {
          int j = q * 16 + i;
          float a = __fadd_rn(ACT(j), bL[j]);          // bias after conv
          ACT(j) = ((allow >> j) & 1ull) ? a : 0.0f;
        }
      }

    // ---- selection: sorted top-16 via grouped bitonic ----
    uint32_t run[16];
#pragma unroll
    for (int i = 0; i < 16; ++i)
      run[i] = __float_as_uint(ACT(i)) & 0x7fffffffu;
    bsort16(run);
#pragma unroll
    for (int g = 1; g < 4; ++g) {
      if (g * 16 < N) {
        uint32_t tmp[16];
#pragma unroll
        for (int i = 0; i < 16; ++i)
          tmp[i] = __float_as_uint(ACT(g * 16 + i)) & 0x7fffffffu;
        bsort16(tmp);
#pragma unroll
        for (int i = 0; i < 16; ++i) {   // keep top-16 of the two desc runs
          uint32_t c = tmp[15 - i];
          run[i] = run[i] > c ? run[i] : c;
        }
        bmerge16(run);                   // re-sort (run stays fully sorted)
      }
    }

    uint32_t mb = 0;                     // m = run[K-1], K runtime uniform
#pragma unroll
    for (int i = 0; i < 16; ++i) mb = (i == K - 1) ? run[i] : mb;
    float m = __uint_as_float(mb);
    int quota = 0;                       // #{i<K: run[i]==m}
#pragma unroll
    for (int i = 0; i < 16; ++i) quota += (i < K && run[i] == mb) ? 1 : 0;

    // ---- keep + store + mask (quarter-guarded; padded j harmless).
    // Store: uniform SGPR base per channel + tofs4 voffset (saddr form). ----
    uint64_t msk = 0;
#pragma unroll
    for (int q = 0; q < 4; ++q)
      if (q * 16 < N) {
#pragma unroll
        for (int i = 0; i < 16; ++i) {
          int j = q * 16 + i;
          float aj = fabsf(ACT(j));
          bool eq = (aj == m);
          bool keep = (aj > m) || (eq && quota > 0);
          quota -= eq ? 1 : 0;
          float v = keep ? ACT(j) : 0.0f;
          *(float*)(outB + (size_t)(ch0 + j) * PLANE * 4 + tofs4) = v;
          msk |= (v != 0.0f) ? (1ull << j) : 0ull;
        }
      }

    if (lvl < 3) allow = spread_pairs(msk, cN[lvl + 1]);
  }
}

extern "C" void kernel_launch(void* const* d_in, const int* in_sizes, int n_in,
                              void* d_out, int out_size, void* d_ws, size_t ws_size,
                              hipStream_t stream) {
  const float* x = (const float*)d_in[0];
  const float* w = (const float*)d_in[1];
  const float* b = (const float*)d_in[2];
  float* out = (float*)d_out;

  wprep<<<dim3((4 * 27 * 64 + 255) / 256), dim3(256), 0, stream>>>(w, b);
  dim3 blk(128), grid((PIX + 127) / 128);
  hrtk_main<<<grid, blk, 0, stream>>>(x, out);
}